// Round 1
// baseline (81.592 us; speedup 1.0000x reference)
//
#include <hip/hip_runtime.h>
#include <hip/hip_bf16.h>
#include <math.h>

#define BS 128
#define NQ 300
#define NT 16

// ---------------------------------------------------------------------------
// Kernel 1: cost matrix C[b][q][t] = 5*L1 + 2*(-giou) + 1*(-p1)
// ---------------------------------------------------------------------------
__global__ void cost_kernel(const float* __restrict__ pred_boxes,   // [BS,NQ,4] cxcywh
                            const float* __restrict__ logits_b,     // [BS,NQ,2]
                            const float* __restrict__ tgt_boxes,    // [BS,NT,5] (cls,cx,cy,w,h)
                            float* __restrict__ C)                  // [BS,NQ,NT]
{
    int idx = blockIdx.x * blockDim.x + threadIdx.x;
    if (idx >= BS * NQ * NT) return;
    int t  = idx & (NT - 1);
    int qb = idx >> 4;                 // b*NQ + q
    int b  = qb / NQ;

    const float* p  = pred_boxes + (size_t)qb * 4;
    const float* l  = logits_b   + (size_t)qb * 2;
    const float* tg = tgt_boxes  + ((size_t)b * NT + t) * 5 + 1;

    float pcx = p[0], pcy = p[1], pw = p[2], ph = p[3];
    float tcx = tg[0], tcy = tg[1], tw = tg[2], th = tg[3];

    // L1 in cxcywh space
    float cost_bbox = fabsf(pcx - tcx) + fabsf(pcy - tcy) + fabsf(pw - tw) + fabsf(ph - th);

    // xyxy
    float ax1 = pcx - 0.5f * pw, ay1 = pcy - 0.5f * ph;
    float ax2 = pcx + 0.5f * pw, ay2 = pcy + 0.5f * ph;
    float bx1 = tcx - 0.5f * tw, by1 = tcy - 0.5f * th;
    float bx2 = tcx + 0.5f * tw, by2 = tcy + 0.5f * th;

    float area_a = (ax2 - ax1) * (ay2 - ay1);
    float area_b = (bx2 - bx1) * (by2 - by1);

    float ltx = fmaxf(ax1, bx1), lty = fmaxf(ay1, by1);
    float rbx = fminf(ax2, bx2), rby = fminf(ay2, by2);
    float wx = fmaxf(rbx - ltx, 0.0f), wy = fmaxf(rby - lty, 0.0f);
    float inter = wx * wy;
    float uni = area_a + area_b - inter;
    float iou = inter / uni;

    float ex1 = fminf(ax1, bx1), ey1 = fminf(ay1, by1);
    float ex2 = fmaxf(ax2, bx2), ey2 = fmaxf(ay2, by2);
    float ewx = fmaxf(ex2 - ex1, 0.0f), ewy = fmaxf(ey2 - ey1, 0.0f);
    float area_e = ewx * ewy;
    float giou = iou - (area_e - uni) / area_e;

    // softmax over 2 logits, take prob of class 1 (matches jax.nn.softmax w/ max-sub)
    float l0 = l[0], l1 = l[1];
    float m = fmaxf(l0, l1);
    float e0 = expf(l0 - m), e1 = expf(l1 - m);
    float p1 = e1 / (e0 + e1);

    C[idx] = 5.0f * cost_bbox - 2.0f * giou - p1;
}

// ---------------------------------------------------------------------------
// Kernel 2: per-batch linear_sum_assignment (shortest augmenting path, f64),
// exactly mirroring the numpy reference (transposed: 16 rows x 300 cols).
// One block (1 wave, 64 lanes) per batch.
// ---------------------------------------------------------------------------
__global__ __launch_bounds__(64) void lsa_kernel(const float* __restrict__ C,  // [BS,NQ,NT]
                                                 float* __restrict__ rows_out, // [BS,NT]
                                                 float* __restrict__ cols_out) // [BS,NT]
{
    const int b    = blockIdx.x;
    const int lane = threadIdx.x;

    __shared__ double cost[NT][NQ];     // transposed cost: cost[t][q] = C[b][q][t]
    __shared__ double minv[NQ];
    __shared__ double vdual[NQ];
    __shared__ double u[NT];
    __shared__ int    path[NQ];
    __shared__ int    row4col[NQ];
    __shared__ int    remaining[NQ];
    __shared__ int    col4row[NT];

    const float* Cb = C + (size_t)b * NQ * NT;
    for (int idx = lane; idx < NQ * NT; idx += 64) {
        int q = idx >> 4;
        int t = idx & (NT - 1);
        cost[t][q] = (double)Cb[idx];
    }
    for (int c = lane; c < NQ; c += 64) { vdual[c] = 0.0; row4col[c] = -1; }
    if (lane < NT) { u[lane] = 0.0; col4row[lane] = -1; }
    __syncthreads();

    for (int cur_row = 0; cur_row < NT; ++cur_row) {
        for (int c = lane; c < NQ; c += 64) { minv[c] = 1e300; path[c] = -1; remaining[c] = 1; }
        __syncthreads();

        double shortest = 0.0;
        int i = cur_row;
        int sink = -1;
        int guard = 0;
        while (sink < 0 && guard++ <= NQ) {
            double ui = u[i];
            double bestv = 1e300;
            int    besti = NQ;
            for (int c = lane; c < NQ; c += 64) {
                if (remaining[c]) {
                    double r = shortest + cost[i][c] - ui - vdual[c];
                    if (r < minv[c]) { minv[c] = r; path[c] = i; }
                    double mv = minv[c];
                    // within a lane, c strictly increases -> strict < keeps smallest c on ties
                    if (mv < bestv) { bestv = mv; besti = c; }
                }
            }
            // wave reduction: min value, tie-break smallest column index (== np.argmin)
            for (int off = 32; off >= 1; off >>= 1) {
                double ov = __shfl_xor(bestv, off);
                int    oi = __shfl_xor(besti, off);
                if (ov < bestv || (ov == bestv && oi < besti)) { bestv = ov; besti = oi; }
            }
            if (besti >= NQ) break;   // safety (NaN guard) -- never hit on valid data
            int k = besti;
            shortest = bestv;
            remaining[k] = 0;         // all lanes write the same value
            __syncthreads();
            int rk = row4col[k];
            if (rk == -1) sink = k;
            else          i = rk;
        }
        __syncthreads();

        // dual updates: u[cur_row]+=shortest; for scanned cols j:
        //   if row4col[j]!=-1: u[row4col[j]] += shortest - minv[j]   (rows distinct -> no race)
        //   v[j] -= shortest - minv[j]
        if (lane == 0) u[cur_row] += shortest;
        for (int c = lane; c < NQ; c += 64) {
            if (!remaining[c]) {
                double d = shortest - minv[c];
                int r = row4col[c];
                if (r != -1) u[r] += d;
                vdual[c] -= d;
            }
        }
        __syncthreads();

        // augment along path (serial, lane 0)
        if (lane == 0 && sink >= 0) {
            int j = sink;
            for (int it = 0; it <= NT; ++it) {
                int ii = path[j];
                row4col[j] = ii;
                int tmp = col4row[ii];
                col4row[ii] = j;
                j = tmp;
                if (ii == cur_row) break;
            }
        }
        __syncthreads();
    }

    // order = argsort(col4row) (values distinct); rows = col4row[order], cols = order
    if (lane == 0) {
        int colv[NT], rowv[NT];
        for (int t = 0; t < NT; ++t) { colv[t] = col4row[t]; rowv[t] = t; }
        for (int a = 1; a < NT; ++a) {
            int cv = colv[a], rv = rowv[a];
            int p = a - 1;
            while (p >= 0 && colv[p] > cv) { colv[p + 1] = colv[p]; rowv[p + 1] = rowv[p]; --p; }
            colv[p + 1] = cv; rowv[p + 1] = rv;
        }
        for (int j = 0; j < NT; ++j) {
            rows_out[b * NT + j] = (float)colv[j];
            cols_out[b * NT + j] = (float)rowv[j];
        }
    }
}

extern "C" void kernel_launch(void* const* d_in, const int* in_sizes, int n_in,
                              void* d_out, int out_size, void* d_ws, size_t ws_size,
                              hipStream_t stream) {
    // setup_inputs order: pred_logits (unused), pred_boxes, pred_logits_b, tgt_boxes
    const float* pred_boxes = (const float*)d_in[1];
    const float* logits_b   = (const float*)d_in[2];
    const float* tgt_boxes  = (const float*)d_in[3];

    float* C    = (float*)d_out;                   // [BS,NQ,NT] = 614400
    float* rows = C + (size_t)BS * NQ * NT;        // [BS,NT]    = 2048
    float* cols = rows + (size_t)BS * NT;          // [BS,NT]    = 2048

    const int total = BS * NQ * NT;
    cost_kernel<<<(total + 255) / 256, 256, 0, stream>>>(pred_boxes, logits_b, tgt_boxes, C);
    lsa_kernel<<<BS, 64, 0, stream>>>(C, rows, cols);
}

// Round 2
// 54.954 us; speedup vs baseline: 1.4847x; 1.4847x over previous
//
#include <hip/hip_runtime.h>
#include <hip/hip_bf16.h>
#include <math.h>

#define BS 128
#define NQ 300
#define NT 16
#define CPL 5   // columns per lane: ceil(300/64)

// ---------------------------------------------------------------------------
// Kernel 1: cost matrix C[b][q][t] = 5*L1 + 2*(-giou) + 1*(-p1)
// (unchanged from passing version -- keeps C bit-identical)
// ---------------------------------------------------------------------------
__global__ void cost_kernel(const float* __restrict__ pred_boxes,   // [BS,NQ,4] cxcywh
                            const float* __restrict__ logits_b,     // [BS,NQ,2]
                            const float* __restrict__ tgt_boxes,    // [BS,NT,5] (cls,cx,cy,w,h)
                            float* __restrict__ C)                  // [BS,NQ,NT]
{
    int idx = blockIdx.x * blockDim.x + threadIdx.x;
    if (idx >= BS * NQ * NT) return;
    int t  = idx & (NT - 1);
    int qb = idx >> 4;                 // b*NQ + q
    int b  = qb / NQ;

    const float* p  = pred_boxes + (size_t)qb * 4;
    const float* l  = logits_b   + (size_t)qb * 2;
    const float* tg = tgt_boxes  + ((size_t)b * NT + t) * 5 + 1;

    float pcx = p[0], pcy = p[1], pw = p[2], ph = p[3];
    float tcx = tg[0], tcy = tg[1], tw = tg[2], th = tg[3];

    float cost_bbox = fabsf(pcx - tcx) + fabsf(pcy - tcy) + fabsf(pw - tw) + fabsf(ph - th);

    float ax1 = pcx - 0.5f * pw, ay1 = pcy - 0.5f * ph;
    float ax2 = pcx + 0.5f * pw, ay2 = pcy + 0.5f * ph;
    float bx1 = tcx - 0.5f * tw, by1 = tcy - 0.5f * th;
    float bx2 = tcx + 0.5f * tw, by2 = tcy + 0.5f * th;

    float area_a = (ax2 - ax1) * (ay2 - ay1);
    float area_b = (bx2 - bx1) * (by2 - by1);

    float ltx = fmaxf(ax1, bx1), lty = fmaxf(ay1, by1);
    float rbx = fminf(ax2, bx2), rby = fminf(ay2, by2);
    float wx = fmaxf(rbx - ltx, 0.0f), wy = fmaxf(rby - lty, 0.0f);
    float inter = wx * wy;
    float uni = area_a + area_b - inter;
    float iou = inter / uni;

    float ex1 = fminf(ax1, bx1), ey1 = fminf(ay1, by1);
    float ex2 = fmaxf(ax2, bx2), ey2 = fmaxf(ey2 = ay2 > by2 ? ay2 : by2, ey2);
    // NOTE: the line above must stay semantically fmaxf(ay2,by2); rewritten plainly below.
    ex2 = fmaxf(ax2, bx2);
    float ey2v = fmaxf(ay2, by2);
    float ewx = fmaxf(ex2 - ex1, 0.0f), ewy = fmaxf(ey2v - ey1, 0.0f);
    float area_e = ewx * ewy;
    float giou = iou - (area_e - uni) / area_e;

    float l0 = l[0], l1 = l[1];
    float m = fmaxf(l0, l1);
    float e0 = expf(l0 - m), e1 = expf(l1 - m);
    float p1 = e1 / (e0 + e1);

    C[idx] = 5.0f * cost_bbox - 2.0f * giou - p1;
}

// ---------------------------------------------------------------------------
// Kernel 2: per-batch linear_sum_assignment, register-resident per-column
// state. One block = one wave (64 lanes) per batch. f64 duals/minv (exact
// numpy semantics, identical evaluation order); cost staged in LDS as f32
// (exact -- reference casts the same f32 to f64).
// ---------------------------------------------------------------------------
__global__ __launch_bounds__(64) void lsa_kernel(const float* __restrict__ C,  // [BS,NQ,NT]
                                                 float* __restrict__ rows_out, // [BS,NT]
                                                 float* __restrict__ cols_out) // [BS,NT]
{
    const int b    = blockIdx.x;
    const int lane = threadIdx.x;

    __shared__ float  cost[NT][NQ];    // transposed: cost[t][q] = C[b][q][t]  (19.2 KB)
    __shared__ int    path_s[NQ];
    __shared__ int    row4col_s[NQ];
    __shared__ int    col4row_s[NT];
    __shared__ double u_add[NT];

    const float* Cb = C + (size_t)b * NQ * NT;
    for (int idx = lane; idx < NQ * NT; idx += 64) {
        int q = idx >> 4;
        int t = idx & (NT - 1);
        cost[t][q] = Cb[idx];
    }
    for (int c = lane; c < NQ; c += 64) row4col_s[c] = -1;
    if (lane < NT) { col4row_s[lane] = -1; u_add[lane] = 0.0; }

    // per-lane column state: columns c = lane + 64*j, j in [0,CPL)
    double v_reg[CPL];
    int    r4c_reg[CPL];
    #pragma unroll
    for (int j = 0; j < CPL; ++j) { v_reg[j] = 0.0; r4c_reg[j] = -1; }
    double u_reg = 0.0;                 // u[lane] for lane < NT
    unsigned valid0 = 0;
    #pragma unroll
    for (int j = 0; j < CPL; ++j) if (lane + 64 * j < NQ) valid0 |= (1u << j);
    __syncthreads();

    for (int cur_row = 0; cur_row < NT; ++cur_row) {
        double minv_reg[CPL];
        int    path_reg[CPL];
        #pragma unroll
        for (int j = 0; j < CPL; ++j) { minv_reg[j] = 1e300; path_reg[j] = -1; }
        unsigned rem = valid0;

        double shortest = 0.0;
        int i = cur_row;
        int sink = -1;

        for (int guard = 0; guard <= NQ && sink < 0; ++guard) {
            double ui = __shfl(u_reg, i);
            double bestv = 1e300;
            int    besti = NQ;
            #pragma unroll
            for (int j = 0; j < CPL; ++j) {
                if (rem & (1u << j)) {
                    int c = lane + 64 * j;
                    // identical association order to numpy: ((shortest+cost)-u)-v
                    double r = shortest + (double)cost[i][c] - ui - v_reg[j];
                    if (r < minv_reg[j]) { minv_reg[j] = r; path_reg[j] = i; }
                    double mv = minv_reg[j];
                    if (mv < bestv) { bestv = mv; besti = c; }  // c ascends with j -> first-min
                }
            }
            // wave reduction: min value, tie-break smallest column (== np.argmin)
            for (int off = 32; off >= 1; off >>= 1) {
                double ov = __shfl_xor(bestv, off);
                int    oi = __shfl_xor(besti, off);
                if (ov < bestv || (ov == bestv && oi < besti)) { bestv = ov; besti = oi; }
            }
            if (besti >= NQ) break;     // NaN guard, never hit on valid data
            int k = besti;
            shortest = bestv;
            int jk = k >> 6;
            if ((k & 63) == lane) rem &= ~(1u << jk);
            // row4col[k] from the owning lane's register cache (jk is uniform)
            int rv = r4c_reg[0];
            if (jk == 1) rv = r4c_reg[1];
            else if (jk == 2) rv = r4c_reg[2];
            else if (jk == 3) rv = r4c_reg[3];
            else if (jk == 4) rv = r4c_reg[4];
            int rk = __shfl(rv, k & 63);
            if (rk == -1) sink = k;
            else          i = rk;
        }

        // dual updates: v[scanned] -= d; u[row4col[scanned]] += d (rows distinct).
        #pragma unroll
        for (int j = 0; j < CPL; ++j) {
            unsigned bit = 1u << j;
            if ((valid0 & bit) && !(rem & bit)) {        // scanned column
                double d = shortest - minv_reg[j];
                int r = r4c_reg[j];
                if (r != -1) u_add[r] = d;               // distinct rows, no race
                v_reg[j] -= d;
            }
            if (valid0 & bit) path_s[lane + 64 * j] = path_reg[j];
        }
        __syncthreads();
        if (lane == cur_row) u_reg += shortest;
        if (lane < NT) { u_reg += u_add[lane]; u_add[lane] = 0.0; }

        // augment along path (serial, lane 0; chain length <= NT)
        if (lane == 0 && sink >= 0) {
            int j = sink;
            for (int it = 0; it <= NT; ++it) {
                int ii = path_s[j];
                row4col_s[j] = ii;
                int tmp = col4row_s[ii];
                col4row_s[ii] = j;
                j = tmp;
                if (ii == cur_row) break;
            }
        }
        __syncthreads();
        // refresh row4col register cache
        #pragma unroll
        for (int j = 0; j < CPL; ++j) {
            if (valid0 & (1u << j)) r4c_reg[j] = row4col_s[lane + 64 * j];
        }
    }

    // order = argsort(col4row) (distinct values); rows = col4row[order], cols = order
    if (lane == 0) {
        int colv[NT], rowv[NT];
        for (int t = 0; t < NT; ++t) { colv[t] = col4row_s[t]; rowv[t] = t; }
        for (int a = 1; a < NT; ++a) {
            int cv = colv[a], rv = rowv[a];
            int p = a - 1;
            while (p >= 0 && colv[p] > cv) { colv[p + 1] = colv[p]; rowv[p + 1] = rowv[p]; --p; }
            colv[p + 1] = cv; rowv[p + 1] = rv;
        }
        for (int j = 0; j < NT; ++j) {
            rows_out[b * NT + j] = (float)colv[j];
            cols_out[b * NT + j] = (float)rowv[j];
        }
    }
}

extern "C" void kernel_launch(void* const* d_in, const int* in_sizes, int n_in,
                              void* d_out, int out_size, void* d_ws, size_t ws_size,
                              hipStream_t stream) {
    const float* pred_boxes = (const float*)d_in[1];
    const float* logits_b   = (const float*)d_in[2];
    const float* tgt_boxes  = (const float*)d_in[3];

    float* C    = (float*)d_out;                   // [BS,NQ,NT]
    float* rows = C + (size_t)BS * NQ * NT;        // [BS,NT]
    float* cols = rows + (size_t)BS * NT;          // [BS,NT]

    const int total = BS * NQ * NT;
    cost_kernel<<<(total + 255) / 256, 256, 0, stream>>>(pred_boxes, logits_b, tgt_boxes, C);
    lsa_kernel<<<BS, 64, 0, stream>>>(C, rows, cols);
}

// Round 3
// 48.557 us; speedup vs baseline: 1.6803x; 1.1317x over previous
//
#include <hip/hip_runtime.h>
#include <hip/hip_bf16.h>
#include <math.h>

#define BS 128
#define NQ 300
#define NT 16
#define CPL 5   // columns per lane: ceil(300/64)

// ---------------------------------------------------------------------------
// Kernel 1: cost matrix C[b][q][t] = 5*L1 + 2*(-giou) + 1*(-p1)
// (same f32 expression order as the passing version)
// ---------------------------------------------------------------------------
__global__ void cost_kernel(const float* __restrict__ pred_boxes,   // [BS,NQ,4] cxcywh
                            const float* __restrict__ logits_b,     // [BS,NQ,2]
                            const float* __restrict__ tgt_boxes,    // [BS,NT,5] (cls,cx,cy,w,h)
                            float* __restrict__ C)                  // [BS,NQ,NT]
{
    int idx = blockIdx.x * blockDim.x + threadIdx.x;
    if (idx >= BS * NQ * NT) return;
    int t  = idx & (NT - 1);
    int qb = idx >> 4;                 // b*NQ + q
    int b  = qb / NQ;

    const float* p  = pred_boxes + (size_t)qb * 4;
    const float* l  = logits_b   + (size_t)qb * 2;
    const float* tg = tgt_boxes  + ((size_t)b * NT + t) * 5 + 1;

    float pcx = p[0], pcy = p[1], pw = p[2], ph = p[3];
    float tcx = tg[0], tcy = tg[1], tw = tg[2], th = tg[3];

    float cost_bbox = fabsf(pcx - tcx) + fabsf(pcy - tcy) + fabsf(pw - tw) + fabsf(ph - th);

    float ax1 = pcx - 0.5f * pw, ay1 = pcy - 0.5f * ph;
    float ax2 = pcx + 0.5f * pw, ay2 = pcy + 0.5f * ph;
    float bx1 = tcx - 0.5f * tw, by1 = tcy - 0.5f * th;
    float bx2 = tcx + 0.5f * tw, by2 = tcy + 0.5f * th;

    float area_a = (ax2 - ax1) * (ay2 - ay1);
    float area_b = (bx2 - bx1) * (by2 - by1);

    float ltx = fmaxf(ax1, bx1), lty = fmaxf(ay1, by1);
    float rbx = fminf(ax2, bx2), rby = fminf(ay2, by2);
    float wx = fmaxf(rbx - ltx, 0.0f), wy = fmaxf(rby - lty, 0.0f);
    float inter = wx * wy;
    float uni = area_a + area_b - inter;
    float iou = inter / uni;

    float ex1 = fminf(ax1, bx1), ey1 = fminf(ay1, by1);
    float ex2 = fmaxf(ax2, bx2);
    float ey2 = fmaxf(ay2, by2);
    float ewx = fmaxf(ex2 - ex1, 0.0f), ewy = fmaxf(ey2 - ey1, 0.0f);
    float area_e = ewx * ewy;
    float giou = iou - (area_e - uni) / area_e;

    float l0 = l[0], l1 = l[1];
    float m = fmaxf(l0, l1);
    float e0 = expf(l0 - m), e1 = expf(l1 - m);
    float p1 = e1 / (e0 + e1);

    C[idx] = 5.0f * cost_bbox - 2.0f * giou - p1;
}

// ---------------------------------------------------------------------------
// DPP helpers: VALU-latency cross-lane (no LDS pipe)
// ---------------------------------------------------------------------------
__device__ __forceinline__ int dppmov_111(int x){ return __builtin_amdgcn_update_dpp(x, x, 0x111, 0xF, 0xF, false); } // row_shr:1
__device__ __forceinline__ int dppmov_112(int x){ return __builtin_amdgcn_update_dpp(x, x, 0x112, 0xF, 0xF, false); } // row_shr:2
__device__ __forceinline__ int dppmov_114(int x){ return __builtin_amdgcn_update_dpp(x, x, 0x114, 0xF, 0xF, false); } // row_shr:4
__device__ __forceinline__ int dppmov_118(int x){ return __builtin_amdgcn_update_dpp(x, x, 0x118, 0xF, 0xF, false); } // row_shr:8
__device__ __forceinline__ int dppmov_142(int x){ return __builtin_amdgcn_update_dpp(x, x, 0x142, 0xF, 0xF, false); } // row_bcast:15
__device__ __forceinline__ int dppmov_143(int x){ return __builtin_amdgcn_update_dpp(x, x, 0x143, 0xF, 0xF, false); } // row_bcast:31

union DI { double d; int i[2]; };

#define DPP_ARGMIN_STEP(MOV)                                            \
    {                                                                   \
        DI cv; cv.d = bestv;                                            \
        int plo  = MOV(cv.i[0]);                                        \
        int phi  = MOV(cv.i[1]);                                        \
        int pidx = MOV(besti);                                          \
        DI pv; pv.i[0] = plo; pv.i[1] = phi;                            \
        if (pv.d < bestv || (pv.d == bestv && pidx < besti)) {          \
            bestv = pv.d; besti = pidx;                                 \
        }                                                               \
    }

// ---------------------------------------------------------------------------
// Kernel 2: per-batch linear_sum_assignment; one wave per batch; per-column
// state in registers; wave-uniform scalars via readlane; DPP argmin.
// f64 duals/minv with numpy-identical evaluation order.
// ---------------------------------------------------------------------------
__global__ __launch_bounds__(64) void lsa_kernel(const float* __restrict__ C,  // [BS,NQ,NT]
                                                 float* __restrict__ rows_out, // [BS,NT]
                                                 float* __restrict__ cols_out) // [BS,NT]
{
    const int b    = blockIdx.x;
    const int lane = threadIdx.x;

    __shared__ float  cost[NT][NQ];    // transposed: cost[t][q] = C[b][q][t]
    __shared__ int    path_s[NQ];
    __shared__ int    row4col_s[NQ];
    __shared__ int    col4row_s[NT];
    __shared__ double u_add[NT];

    // stage C[b] -> LDS (float4 vectorized; t0 in {0,4,8,12} never crosses q)
    const float4* Cb4 = reinterpret_cast<const float4*>(C + (size_t)b * NQ * NT);
    for (int idx4 = lane; idx4 < (NQ * NT) / 4; idx4 += 64) {
        float4 v = Cb4[idx4];
        int base = idx4 * 4;
        int q = base >> 4, t0 = base & 15;
        cost[t0 + 0][q] = v.x;
        cost[t0 + 1][q] = v.y;
        cost[t0 + 2][q] = v.z;
        cost[t0 + 3][q] = v.w;
    }
    for (int c = lane; c < NQ; c += 64) row4col_s[c] = -1;
    if (lane < NT) { col4row_s[lane] = -1; u_add[lane] = 0.0; }

    // per-lane column state: columns c = lane + 64*j
    double v_reg[CPL];
    int    r4c_reg[CPL];
    #pragma unroll
    for (int j = 0; j < CPL; ++j) { v_reg[j] = 0.0; r4c_reg[j] = -1; }
    double u_reg = 0.0;                 // u[lane] for lane < NT
    unsigned valid0 = 0;
    #pragma unroll
    for (int j = 0; j < CPL; ++j) if (lane + 64 * j < NQ) valid0 |= (1u << j);
    __syncthreads();

    for (int cur_row = 0; cur_row < NT; ++cur_row) {
        double minv_reg[CPL];
        int    path_reg[CPL];
        #pragma unroll
        for (int j = 0; j < CPL; ++j) { minv_reg[j] = 1e300; path_reg[j] = -1; }
        unsigned rem = valid0;

        double shortest = 0.0;
        int i = cur_row;                // wave-uniform (scalar)
        int sink = -1;

        for (int guard = 0; guard <= NQ && sink < 0; ++guard) {
            // ui = u[i] via readlane (i uniform)
            DI uu; uu.d = u_reg;
            DI ur;
            ur.i[0] = __builtin_amdgcn_readlane(uu.i[0], i);
            ur.i[1] = __builtin_amdgcn_readlane(uu.i[1], i);
            double ui = ur.d;

            // relax lane's columns; candidate values (branchless tree below)
            double cv[CPL];
            #pragma unroll
            for (int j = 0; j < CPL; ++j) {
                unsigned bit = 1u << j;
                if (rem & bit) {
                    int c = lane + 64 * j;
                    // numpy order: ((shortest + cost) - u) - v
                    double r = shortest + (double)cost[i][c] - ui - v_reg[j];
                    if (r < minv_reg[j]) { minv_reg[j] = r; path_reg[j] = i; }
                }
                cv[j] = (rem & bit) ? minv_reg[j] : 1e300;
            }
            // per-lane argmin tree, ties keep lower column (left operand)
            double bestv; int besti;
            {
                double v0 = cv[0]; int c0 = lane;
                double v1 = cv[1]; int c1 = lane + 64;
                double v2 = cv[2]; int c2 = lane + 128;
                double v3 = cv[3]; int c3 = lane + 192;
                double v4 = cv[4]; int c4 = lane + 256;
                double va = v0; int ca = c0;
                if (v1 < va) { va = v1; ca = c1; }
                double vb = v2; int cb = c2;
                if (v3 < vb) { vb = v3; cb = c3; }
                if (vb < va) { va = vb; ca = cb; }
                if (v4 < va) { va = v4; ca = c4; }
                bestv = va; besti = (va >= 1e300) ? NQ : ca;
            }
            // wave argmin via DPP scan (VALU latency), result lands in lane 63
            DPP_ARGMIN_STEP(dppmov_111);
            DPP_ARGMIN_STEP(dppmov_112);
            DPP_ARGMIN_STEP(dppmov_114);
            DPP_ARGMIN_STEP(dppmov_118);
            DPP_ARGMIN_STEP(dppmov_142);
            DPP_ARGMIN_STEP(dppmov_143);

            DI bv; bv.d = bestv;
            DI sv;
            sv.i[0] = __builtin_amdgcn_readlane(bv.i[0], 63);
            sv.i[1] = __builtin_amdgcn_readlane(bv.i[1], 63);
            int k   = __builtin_amdgcn_readlane(besti, 63);
            if (k >= NQ) break;         // NaN guard; never hit on valid data
            shortest = sv.d;

            int jk = k >> 6;            // uniform
            if ((k & 63) == lane) rem &= ~(1u << jk);

            int rv = r4c_reg[0];
            if (jk == 1) rv = r4c_reg[1];
            else if (jk == 2) rv = r4c_reg[2];
            else if (jk == 3) rv = r4c_reg[3];
            else if (jk == 4) rv = r4c_reg[4];
            int rk = __builtin_amdgcn_readlane(rv, k & 63);
            if (rk == -1) sink = k;
            else          i = rk;
        }

        // dual updates (scanned == popped columns): v[j] -= d; u[row4col[j]] += d
        #pragma unroll
        for (int j = 0; j < CPL; ++j) {
            unsigned bit = 1u << j;
            if ((valid0 & bit) && !(rem & bit)) {
                double d = shortest - minv_reg[j];
                int r = r4c_reg[j];
                if (r != -1) u_add[r] = d;               // rows distinct, no race
                v_reg[j] -= d;
            }
            if (valid0 & bit) path_s[lane + 64 * j] = path_reg[j];
        }
        __syncthreads();
        if (lane == cur_row) u_reg += shortest;
        if (lane < NT) { u_reg += u_add[lane]; u_add[lane] = 0.0; }

        // augment along path (serial, lane 0; chain length <= NT)
        if (lane == 0 && sink >= 0) {
            int j = sink;
            for (int it = 0; it <= NT; ++it) {
                int ii = path_s[j];
                row4col_s[j] = ii;
                int tmp = col4row_s[ii];
                col4row_s[ii] = j;
                j = tmp;
                if (ii == cur_row) break;
            }
        }
        __syncthreads();
        #pragma unroll
        for (int j = 0; j < CPL; ++j) {
            if (valid0 & (1u << j)) r4c_reg[j] = row4col_s[lane + 64 * j];
        }
    }

    // order = argsort(col4row) (distinct values); rows = col4row[order], cols = order
    if (lane == 0) {
        int colv[NT], rowv[NT];
        for (int t = 0; t < NT; ++t) { colv[t] = col4row_s[t]; rowv[t] = t; }
        for (int a = 1; a < NT; ++a) {
            int cvv = colv[a], rvv = rowv[a];
            int p = a - 1;
            while (p >= 0 && colv[p] > cvv) { colv[p + 1] = colv[p]; rowv[p + 1] = rowv[p]; --p; }
            colv[p + 1] = cvv; rowv[p + 1] = rvv;
        }
        for (int j = 0; j < NT; ++j) {
            rows_out[b * NT + j] = (float)colv[j];
            cols_out[b * NT + j] = (float)rowv[j];
        }
    }
}

extern "C" void kernel_launch(void* const* d_in, const int* in_sizes, int n_in,
                              void* d_out, int out_size, void* d_ws, size_t ws_size,
                              hipStream_t stream) {
    const float* pred_boxes = (const float*)d_in[1];
    const float* logits_b   = (const float*)d_in[2];
    const float* tgt_boxes  = (const float*)d_in[3];

    float* C    = (float*)d_out;                   // [BS,NQ,NT]
    float* rows = C + (size_t)BS * NQ * NT;        // [BS,NT]
    float* cols = rows + (size_t)BS * NT;          // [BS,NT]

    const int total = BS * NQ * NT;
    cost_kernel<<<(total + 255) / 256, 256, 0, stream>>>(pred_boxes, logits_b, tgt_boxes, C);
    lsa_kernel<<<BS, 64, 0, stream>>>(C, rows, cols);
}

// Round 5
// 31.409 us; speedup vs baseline: 2.5977x; 1.5459x over previous
//
#include <hip/hip_runtime.h>
#include <hip/hip_bf16.h>
#include <math.h>

#define BS 128
#define NQ 300
#define NT 16
#define CPL 5   // columns per lane: 300 = 60 lanes * 5 cols, lanes 60..63 idle

// ---------------------------------------------------------------------------
// Kernel 1: cost matrix C[b][q][t] = 5*L1 + 2*(-giou) + 1*(-p1)
// (same f32 expression order as the passing version -- keeps C bit-identical)
// ---------------------------------------------------------------------------
__global__ void cost_kernel(const float* __restrict__ pred_boxes,   // [BS,NQ,4] cxcywh
                            const float* __restrict__ logits_b,     // [BS,NQ,2]
                            const float* __restrict__ tgt_boxes,    // [BS,NT,5] (cls,cx,cy,w,h)
                            float* __restrict__ C)                  // [BS,NQ,NT]
{
    int idx = blockIdx.x * blockDim.x + threadIdx.x;
    if (idx >= BS * NQ * NT) return;
    int t  = idx & (NT - 1);
    int qb = idx >> 4;                 // b*NQ + q
    int b  = qb / NQ;

    const float* p  = pred_boxes + (size_t)qb * 4;
    const float* l  = logits_b   + (size_t)qb * 2;
    const float* tg = tgt_boxes  + ((size_t)b * NT + t) * 5 + 1;

    float pcx = p[0], pcy = p[1], pw = p[2], ph = p[3];
    float tcx = tg[0], tcy = tg[1], tw = tg[2], th = tg[3];

    float cost_bbox = fabsf(pcx - tcx) + fabsf(pcy - tcy) + fabsf(pw - tw) + fabsf(ph - th);

    float ax1 = pcx - 0.5f * pw, ay1 = pcy - 0.5f * ph;
    float ax2 = pcx + 0.5f * pw, ay2 = pcy + 0.5f * ph;
    float bx1 = tcx - 0.5f * tw, by1 = tcy - 0.5f * th;
    float bx2 = tcx + 0.5f * tw, by2 = tcy + 0.5f * th;

    float area_a = (ax2 - ax1) * (ay2 - ay1);
    float area_b = (bx2 - bx1) * (by2 - by1);

    float ltx = fmaxf(ax1, bx1), lty = fmaxf(ay1, by1);
    float rbx = fminf(ax2, bx2), rby = fminf(ay2, by2);
    float wx = fmaxf(rbx - ltx, 0.0f), wy = fmaxf(rby - lty, 0.0f);
    float inter = wx * wy;
    float uni = area_a + area_b - inter;
    float iou = inter / uni;

    float ex1 = fminf(ax1, bx1), ey1 = fminf(ay1, by1);
    float ex2 = fmaxf(ax2, bx2);
    float ey2 = fmaxf(ay2, by2);
    float ewx = fmaxf(ex2 - ex1, 0.0f), ewy = fmaxf(ey2 - ey1, 0.0f);
    float area_e = ewx * ewy;
    float giou = iou - (area_e - uni) / area_e;

    float l0 = l[0], l1 = l[1];
    float m = fmaxf(l0, l1);
    float e0 = expf(l0 - m), e1 = expf(l1 - m);
    float p1 = e1 / (e0 + e1);

    C[idx] = 5.0f * cost_bbox - 2.0f * giou - p1;
}

// ---------------------------------------------------------------------------
// helpers
// ---------------------------------------------------------------------------
union DI { double d; int i[2]; };

// f64 value-only min reduce step via DPP (VALU latency, no index carry)
#define DPP_MIN_STEP(CTRL)                                                    \
    {                                                                         \
        DI a_; a_.d = bestv;                                                  \
        DI p_;                                                                \
        p_.i[0] = __builtin_amdgcn_update_dpp(a_.i[0], a_.i[0], CTRL, 0xF, 0xF, false); \
        p_.i[1] = __builtin_amdgcn_update_dpp(a_.i[1], a_.i[1], CTRL, 0xF, 0xF, false); \
        bestv = fmin(bestv, p_.d);                                            \
    }

__device__ __forceinline__ double readlane_d(double x, int lane) {
    DI a; a.d = x;
    DI r;
    r.i[0] = __builtin_amdgcn_readlane(a.i[0], lane);
    r.i[1] = __builtin_amdgcn_readlane(a.i[1], lane);
    return r.d;
}

// ---------------------------------------------------------------------------
// Kernel 2: per-batch linear_sum_assignment (JV shortest augmenting path),
// one wave per batch. Columns lane-contiguous (c = 5*lane + j). All mutable
// assignment state in registers; cost tile + u_add scatter in LDS.
// f64 duals/minv, numpy-identical evaluation order and argmin tie-breaks.
// ---------------------------------------------------------------------------
__global__ __launch_bounds__(64) void lsa_kernel(const float* __restrict__ C,  // [BS,NQ,NT]
                                                 float* __restrict__ rows_out, // [BS,NT]
                                                 float* __restrict__ cols_out) // [BS,NT]
{
    const int b    = blockIdx.x;
    const int lane = threadIdx.x;

    __shared__ float  cost[NT][NQ];    // transposed: cost[t][q] = C[b][q][t]
    __shared__ double u_add[NT];

    // stage C[b] -> LDS (float4; 4 consecutive t for one q)
    const float4* Cb4 = reinterpret_cast<const float4*>(C + (size_t)b * NQ * NT);
    for (int idx4 = lane; idx4 < (NQ * NT) / 4; idx4 += 64) {
        float4 v = Cb4[idx4];
        int base = idx4 * 4;
        int q = base >> 4, t0 = base & 15;
        cost[t0 + 0][q] = v.x;
        cost[t0 + 1][q] = v.y;
        cost[t0 + 2][q] = v.z;
        cost[t0 + 3][q] = v.w;
    }
    if (lane < NT) u_add[lane] = 0.0;

    const bool has_cols = (lane < 60);
    const int  cbase    = has_cols ? lane * CPL : 0;   // idle lanes read col 0 (safe)
    const unsigned valid0 = has_cols ? 0x1Fu : 0u;

    double v_reg[CPL];        // v dual for column cbase+j
    int    r4c_reg[CPL];      // row4col for column cbase+j
    int    path_reg[CPL];     // path   for column cbase+j
    #pragma unroll
    for (int j = 0; j < CPL; ++j) { v_reg[j] = 0.0; r4c_reg[j] = -1; path_reg[j] = -1; }
    double u_reg   = 0.0;     // u[lane] on lanes 0..15
    int    c4r_reg = -1;      // col4row[lane] on lanes 0..15
    __syncthreads();

    for (int cur_row = 0; cur_row < NT; ++cur_row) {
        double minv_reg[CPL];
        #pragma unroll
        for (int j = 0; j < CPL; ++j) { minv_reg[j] = 1e300; path_reg[j] = -1; }
        unsigned rem = valid0;

        double shortest = 0.0;
        int i = cur_row;             // wave-uniform
        int sink = -1;

        for (int guard = 0; guard <= NT && sink < 0; ++guard) {
            const double ui = readlane_d(u_reg, i);

            // load this lane's 5 cost entries of row i (stride-5 -> 2-way banks, free)
            const float* crow = &cost[0][0] + i * NQ + cbase;
            float cf[CPL];
            #pragma unroll
            for (int j = 0; j < CPL; ++j) cf[j] = crow[j];

            // relax + per-lane argmin (ascending j => first-min kept)
            double bestv = 1e300;
            int    bj    = 0;
            #pragma unroll
            for (int j = 0; j < CPL; ++j) {
                unsigned bit = 1u << j;
                if (rem & bit) {
                    // numpy order: ((shortest + cost) - u) - v
                    double r = ((shortest + (double)cf[j]) - ui) - v_reg[j];
                    if (r < minv_reg[j]) { minv_reg[j] = r; path_reg[j] = i; }
                }
                double cv = (rem & bit) ? minv_reg[j] : 1e300;
                if (cv < bestv) { bestv = cv; bj = j; }
            }
            int bestc = cbase + bj;

            // wave min (value only): 6 DPP steps, total lands in lane 63
            DPP_MIN_STEP(0x111)   // row_shr:1
            DPP_MIN_STEP(0x112)   // row_shr:2
            DPP_MIN_STEP(0x114)   // row_shr:4
            DPP_MIN_STEP(0x118)   // row_shr:8
            DPP_MIN_STEP(0x142)   // row_bcast:15
            DPP_MIN_STEP(0x143)   // row_bcast:31

            const double m = readlane_d(bestv, 63);
            // first occurrence == smallest column: smallest tied lane,
            // per-lane tree already kept smallest j
            unsigned long long tied = __ballot(bestv == m);
            if (tied == 0ull) break;                    // NaN guard; never on valid data
            int l = __ffsll((unsigned long long)tied) - 1;
            int k = __builtin_amdgcn_readlane(bestc, l);
            shortest = m;

            int owner = k / CPL;
            int slot  = k - owner * CPL;                // uniform
            if (lane == owner) rem &= ~(1u << slot);

            // row4col[k] from owner lane's registers
            int r0 = __builtin_amdgcn_readlane(r4c_reg[0], owner);
            int r1 = __builtin_amdgcn_readlane(r4c_reg[1], owner);
            int r2 = __builtin_amdgcn_readlane(r4c_reg[2], owner);
            int r3 = __builtin_amdgcn_readlane(r4c_reg[3], owner);
            int r4 = __builtin_amdgcn_readlane(r4c_reg[4], owner);
            int rk = (slot == 0) ? r0 : (slot == 1) ? r1 : (slot == 2) ? r2
                   : (slot == 3) ? r3 : r4;
            if (rk == -1) sink = k;
            else          i = rk;
        }

        // dual updates: scanned (= popped) columns j: d = shortest - minv[j];
        // u[row4col[j]] += d (rows distinct), v[j] -= d
        #pragma unroll
        for (int j = 0; j < CPL; ++j) {
            unsigned bit = 1u << j;
            if ((valid0 & bit) && !(rem & bit)) {
                double d = shortest - minv_reg[j];
                int r = r4c_reg[j];
                if (r != -1) u_add[r] = d;
                v_reg[j] -= d;
            }
        }
        __syncthreads();
        if (lane == cur_row) u_reg += shortest;
        if (lane < NT) { u_reg += u_add[lane]; u_add[lane] = 0.0; }
        __syncthreads();

        // augment along path: uniform scalar walk on registers
        if (sink >= 0) {
            int j = sink;
            #pragma unroll 1
            for (int it = 0; it <= NT; ++it) {
                int ow = j / CPL;
                int sl = j - ow * CPL;
                int p0 = __builtin_amdgcn_readlane(path_reg[0], ow);
                int p1 = __builtin_amdgcn_readlane(path_reg[1], ow);
                int p2 = __builtin_amdgcn_readlane(path_reg[2], ow);
                int p3 = __builtin_amdgcn_readlane(path_reg[3], ow);
                int p4 = __builtin_amdgcn_readlane(path_reg[4], ow);
                int ii = (sl == 0) ? p0 : (sl == 1) ? p1 : (sl == 2) ? p2
                       : (sl == 3) ? p3 : p4;
                // row4col[j] = ii  (owner lane, uniform slot)
                bool me = (lane == ow);
                r4c_reg[0] = (me && sl == 0) ? ii : r4c_reg[0];
                r4c_reg[1] = (me && sl == 1) ? ii : r4c_reg[1];
                r4c_reg[2] = (me && sl == 2) ? ii : r4c_reg[2];
                r4c_reg[3] = (me && sl == 3) ? ii : r4c_reg[3];
                r4c_reg[4] = (me && sl == 4) ? ii : r4c_reg[4];
                // swap: tmp = col4row[ii]; col4row[ii] = j; j = tmp
                // (ii, j wave-uniform -> predicated per-lane update, no writelane)
                int tmp = __builtin_amdgcn_readlane(c4r_reg, ii);
                c4r_reg = (lane == ii) ? j : c4r_reg;
                j = tmp;
                if (ii == cur_row) break;
            }
        }
    }

    // outputs: order = argsort(col4row) via rank (values distinct);
    // rows_out[rank_t] = col4row[t]; cols_out[rank_t] = t
    int myval = c4r_reg;
    int rank = 0;
    #pragma unroll
    for (int s = 0; s < NT; ++s) {
        int vs = __builtin_amdgcn_readlane(c4r_reg, s);
        rank += (vs < myval) ? 1 : 0;
    }
    if (lane < NT) {
        rows_out[b * NT + rank] = (float)myval;
        cols_out[b * NT + rank] = (float)lane;
    }
}

extern "C" void kernel_launch(void* const* d_in, const int* in_sizes, int n_in,
                              void* d_out, int out_size, void* d_ws, size_t ws_size,
                              hipStream_t stream) {
    const float* pred_boxes = (const float*)d_in[1];
    const float* logits_b   = (const float*)d_in[2];
    const float* tgt_boxes  = (const float*)d_in[3];

    float* C    = (float*)d_out;                   // [BS,NQ,NT]
    float* rows = C + (size_t)BS * NQ * NT;        // [BS,NT]
    float* cols = rows + (size_t)BS * NT;          // [BS,NT]

    const int total = BS * NQ * NT;
    cost_kernel<<<(total + 255) / 256, 256, 0, stream>>>(pred_boxes, logits_b, tgt_boxes, C);
    lsa_kernel<<<BS, 64, 0, stream>>>(C, rows, cols);
}

// Round 6
// 28.267 us; speedup vs baseline: 2.8864x; 1.1112x over previous
//
#include <hip/hip_runtime.h>
#include <hip/hip_bf16.h>
#include <math.h>

#define BS 128
#define NQ 300
#define NT 16
#define CPL 5   // columns per lane: 300 = 60 lanes * 5 cols, lanes 60..63 idle

// ---------------------------------------------------------------------------
// Kernel 1: cost matrix C[b][q][t] = 5*L1 + 2*(-giou) + 1*(-p1)
// (byte-identical to the passing version -- keeps C bit-identical)
// ---------------------------------------------------------------------------
__global__ void cost_kernel(const float* __restrict__ pred_boxes,   // [BS,NQ,4] cxcywh
                            const float* __restrict__ logits_b,     // [BS,NQ,2]
                            const float* __restrict__ tgt_boxes,    // [BS,NT,5] (cls,cx,cy,w,h)
                            float* __restrict__ C)                  // [BS,NQ,NT]
{
    int idx = blockIdx.x * blockDim.x + threadIdx.x;
    if (idx >= BS * NQ * NT) return;
    int t  = idx & (NT - 1);
    int qb = idx >> 4;                 // b*NQ + q
    int b  = qb / NQ;

    const float* p  = pred_boxes + (size_t)qb * 4;
    const float* l  = logits_b   + (size_t)qb * 2;
    const float* tg = tgt_boxes  + ((size_t)b * NT + t) * 5 + 1;

    float pcx = p[0], pcy = p[1], pw = p[2], ph = p[3];
    float tcx = tg[0], tcy = tg[1], tw = tg[2], th = tg[3];

    float cost_bbox = fabsf(pcx - tcx) + fabsf(pcy - tcy) + fabsf(pw - tw) + fabsf(ph - th);

    float ax1 = pcx - 0.5f * pw, ay1 = pcy - 0.5f * ph;
    float ax2 = pcx + 0.5f * pw, ay2 = pcy + 0.5f * ph;
    float bx1 = tcx - 0.5f * tw, by1 = tcy - 0.5f * th;
    float bx2 = tcx + 0.5f * tw, by2 = tcy + 0.5f * th;

    float area_a = (ax2 - ax1) * (ay2 - ay1);
    float area_b = (bx2 - bx1) * (by2 - by1);

    float ltx = fmaxf(ax1, bx1), lty = fmaxf(ay1, by1);
    float rbx = fminf(ax2, bx2), rby = fminf(ay2, by2);
    float wx = fmaxf(rbx - ltx, 0.0f), wy = fmaxf(rby - lty, 0.0f);
    float inter = wx * wy;
    float uni = area_a + area_b - inter;
    float iou = inter / uni;

    float ex1 = fminf(ax1, bx1), ey1 = fminf(ay1, by1);
    float ex2 = fmaxf(ax2, bx2);
    float ey2 = fmaxf(ay2, by2);
    float ewx = fmaxf(ex2 - ex1, 0.0f), ewy = fmaxf(ey2 - ey1, 0.0f);
    float area_e = ewx * ewy;
    float giou = iou - (area_e - uni) / area_e;

    float l0 = l[0], l1 = l[1];
    float m = fmaxf(l0, l1);
    float e0 = expf(l0 - m), e1 = expf(l1 - m);
    float p1 = e1 / (e0 + e1);

    C[idx] = 5.0f * cost_bbox - 2.0f * giou - p1;
}

// ---------------------------------------------------------------------------
// helpers
// ---------------------------------------------------------------------------
union DI { double d; int i[2]; };

// f64 value-only min reduce step via DPP (VALU latency, no index carry)
#define DPP_MIN_STEP(CTRL)                                                    \
    {                                                                         \
        DI a_; a_.d = bestv;                                                  \
        DI p_;                                                                \
        p_.i[0] = __builtin_amdgcn_update_dpp(a_.i[0], a_.i[0], CTRL, 0xF, 0xF, false); \
        p_.i[1] = __builtin_amdgcn_update_dpp(a_.i[1], a_.i[1], CTRL, 0xF, 0xF, false); \
        bestv = fmin(bestv, p_.d);                                            \
    }

// f32 value-only min reduce step via DPP
#define DPP_MINF_STEP(CTRL)                                                   \
    {                                                                         \
        int p_ = __builtin_amdgcn_update_dpp(__float_as_int(rv), __float_as_int(rv), CTRL, 0xF, 0xF, false); \
        rv = fminf(rv, __int_as_float(p_));                                   \
    }

__device__ __forceinline__ double readlane_d(double x, int lane) {
    DI a; a.d = x;
    DI r;
    r.i[0] = __builtin_amdgcn_readlane(a.i[0], lane);
    r.i[1] = __builtin_amdgcn_readlane(a.i[1], lane);
    return r.d;
}

// select element `slot` (wave-uniform) from a 5-register array
__device__ __forceinline__ int sel5(const int* a, int slot) {
    int r = a[0];
    r = (slot == 1) ? a[1] : r;
    r = (slot == 2) ? a[2] : r;
    r = (slot == 3) ? a[3] : r;
    r = (slot == 4) ? a[4] : r;
    return r;
}

// ---------------------------------------------------------------------------
// Kernel 2: per-batch linear_sum_assignment via JV: row-reduction + greedy
// zero-reduced-cost assignment, then exact f64 Dijkstra augmentation for the
// (typically 0-2) conflicted rows. One wave per batch; columns lane-contiguous
// (c = 5*lane + j); all mutable state in registers.
// Produces the unique optimal matching == numpy reference output.
// ---------------------------------------------------------------------------
__global__ __launch_bounds__(64) void lsa_kernel(const float* __restrict__ C,  // [BS,NQ,NT]
                                                 float* __restrict__ rows_out, // [BS,NT]
                                                 float* __restrict__ cols_out) // [BS,NT]
{
    const int b    = blockIdx.x;
    const int lane = threadIdx.x;

    __shared__ float  cost[NT][NQ];    // transposed: cost[t][q] = C[b][q][t]
    __shared__ double u_add[NT];

    // stage C[b] -> LDS (float4; 4 consecutive t for one q)
    const float4* Cb4 = reinterpret_cast<const float4*>(C + (size_t)b * NQ * NT);
    for (int idx4 = lane; idx4 < (NQ * NT) / 4; idx4 += 64) {
        float4 v = Cb4[idx4];
        int base = idx4 * 4;
        int q = base >> 4, t0 = base & 15;
        cost[t0 + 0][q] = v.x;
        cost[t0 + 1][q] = v.y;
        cost[t0 + 2][q] = v.z;
        cost[t0 + 3][q] = v.w;
    }
    if (lane < NT) u_add[lane] = 0.0;

    const bool has_cols = (lane < 60);
    const int  cbase    = has_cols ? lane * CPL : 0;   // idle lanes read col 0 (safe)
    const unsigned valid0 = has_cols ? 0x1Fu : 0u;

    double v_reg[CPL];        // v dual for column cbase+j
    int    r4c_reg[CPL];      // row4col for column cbase+j
    int    path_reg[CPL];     // path   for column cbase+j
    #pragma unroll
    for (int j = 0; j < CPL; ++j) { v_reg[j] = 0.0; r4c_reg[j] = -1; path_reg[j] = -1; }
    double u_reg   = 0.0;     // u[lane] on lanes 0..15
    int    c4r_reg = -1;      // col4row[lane] on lanes 0..15
    __syncthreads();

    // ---- JV init: u[i] = min_j cost[i][j]; jstar[i] = first argmin ----
    int jstar[NT];
    #pragma unroll
    for (int i = 0; i < NT; ++i) {
        const float* crow = &cost[0][0] + i * NQ + cbase;
        float bv = 1e30f; int bj = 0;
        #pragma unroll
        for (int j = 0; j < CPL; ++j) {
            float c = has_cols ? crow[j] : 1e30f;
            if (c < bv) { bv = c; bj = j; }          // ascending j => first-min
        }
        float rv = bv;
        DPP_MINF_STEP(0x111)   // row_shr:1
        DPP_MINF_STEP(0x112)   // row_shr:2
        DPP_MINF_STEP(0x114)   // row_shr:4
        DPP_MINF_STEP(0x118)   // row_shr:8
        DPP_MINF_STEP(0x142)   // row_bcast:15
        DPP_MINF_STEP(0x143)   // row_bcast:31
        float m = __int_as_float(__builtin_amdgcn_readlane(__float_as_int(rv), 63));
        unsigned long long tied = __ballot(bv == m);
        int l = __ffsll(tied) - 1;                    // smallest lane = smallest col block
        jstar[i] = __builtin_amdgcn_readlane(cbase + bj, l);
        if (lane == i) u_reg = (double)m;             // exact: f32 min == f64 min of casts
    }

    // ---- greedy assignment at zero reduced cost ----
    unsigned unassigned = 0;                          // uniform
    #pragma unroll
    for (int i = 0; i < NT; ++i) {
        int k = jstar[i];
        int owner = k / CPL;                          // uniform
        int slot  = k - owner * CPL;
        int mine  = sel5(r4c_reg, slot);
        int rk    = __builtin_amdgcn_readlane(mine, owner);
        if (rk == -1) {
            bool me = (lane == owner);
            r4c_reg[0] = (me && slot == 0) ? i : r4c_reg[0];
            r4c_reg[1] = (me && slot == 1) ? i : r4c_reg[1];
            r4c_reg[2] = (me && slot == 2) ? i : r4c_reg[2];
            r4c_reg[3] = (me && slot == 3) ? i : r4c_reg[3];
            r4c_reg[4] = (me && slot == 4) ? i : r4c_reg[4];
            c4r_reg    = (lane == i) ? k : c4r_reg;
        } else {
            unassigned |= (1u << i);
        }
    }

    // ---- Dijkstra augmentation for conflicted rows only ----
    for (int cur_row = 0; cur_row < NT; ++cur_row) {
        if (!((unassigned >> cur_row) & 1u)) continue;

        double minv_reg[CPL];
        #pragma unroll
        for (int j = 0; j < CPL; ++j) { minv_reg[j] = 1e300; path_reg[j] = -1; }
        unsigned rem = valid0;

        double shortest = 0.0;
        int i = cur_row;             // wave-uniform
        int sink = -1;

        for (int guard = 0; guard <= NT && sink < 0; ++guard) {
            const double ui = readlane_d(u_reg, i);

            const float* crow = &cost[0][0] + i * NQ + cbase;
            float cf[CPL];
            #pragma unroll
            for (int j = 0; j < CPL; ++j) cf[j] = crow[j];

            // relax + per-lane argmin (ascending j => first-min kept)
            double bestv = 1e300;
            int    bj    = 0;
            #pragma unroll
            for (int j = 0; j < CPL; ++j) {
                unsigned bit = 1u << j;
                if (rem & bit) {
                    // numpy order: ((shortest + cost) - u) - v
                    double r = ((shortest + (double)cf[j]) - ui) - v_reg[j];
                    if (r < minv_reg[j]) { minv_reg[j] = r; path_reg[j] = i; }
                }
                double cv = (rem & bit) ? minv_reg[j] : 1e300;
                if (cv < bestv) { bestv = cv; bj = j; }
            }
            int bestc = cbase + bj;

            DPP_MIN_STEP(0x111)
            DPP_MIN_STEP(0x112)
            DPP_MIN_STEP(0x114)
            DPP_MIN_STEP(0x118)
            DPP_MIN_STEP(0x142)
            DPP_MIN_STEP(0x143)

            const double m = readlane_d(bestv, 63);
            unsigned long long tied = __ballot(bestv == m);
            if (tied == 0ull) break;                    // NaN guard; never on valid data
            int l = __ffsll(tied) - 1;
            int k = __builtin_amdgcn_readlane(bestc, l);
            shortest = m;

            int owner = k / CPL;
            int slot  = k - owner * CPL;                // uniform
            if (lane == owner) rem &= ~(1u << slot);

            int mine = sel5(r4c_reg, slot);
            int rk   = __builtin_amdgcn_readlane(mine, owner);
            if (rk == -1) sink = k;
            else          i = rk;
        }

        // dual updates: scanned (= popped) columns j: d = shortest - minv[j];
        // u[row4col[j]] += d (rows distinct), v[j] -= d
        #pragma unroll
        for (int j = 0; j < CPL; ++j) {
            unsigned bit = 1u << j;
            if ((valid0 & bit) && !(rem & bit)) {
                double d = shortest - minv_reg[j];
                int r = r4c_reg[j];
                if (r != -1) u_add[r] = d;
                v_reg[j] -= d;
            }
        }
        __syncthreads();
        if (lane == cur_row) u_reg += shortest;
        if (lane < NT) { u_reg += u_add[lane]; u_add[lane] = 0.0; }
        __syncthreads();

        // augment along path: uniform scalar walk on registers
        if (sink >= 0) {
            int j = sink;
            #pragma unroll 1
            for (int it = 0; it <= NT; ++it) {
                int ow = j / CPL;
                int sl = j - ow * CPL;
                int pm = sel5(path_reg, sl);
                int ii = __builtin_amdgcn_readlane(pm, ow);
                bool me = (lane == ow);
                r4c_reg[0] = (me && sl == 0) ? ii : r4c_reg[0];
                r4c_reg[1] = (me && sl == 1) ? ii : r4c_reg[1];
                r4c_reg[2] = (me && sl == 2) ? ii : r4c_reg[2];
                r4c_reg[3] = (me && sl == 3) ? ii : r4c_reg[3];
                r4c_reg[4] = (me && sl == 4) ? ii : r4c_reg[4];
                int tmp = __builtin_amdgcn_readlane(c4r_reg, ii);
                c4r_reg = (lane == ii) ? j : c4r_reg;
                j = tmp;
                if (ii == cur_row) break;
            }
        }
    }

    // outputs: order = argsort(col4row) via rank (values distinct);
    // rows_out[rank_t] = col4row[t]; cols_out[rank_t] = t
    int myval = c4r_reg;
    int rank = 0;
    #pragma unroll
    for (int s = 0; s < NT; ++s) {
        int vs = __builtin_amdgcn_readlane(c4r_reg, s);
        rank += (vs < myval) ? 1 : 0;
    }
    if (lane < NT) {
        rows_out[b * NT + rank] = (float)myval;
        cols_out[b * NT + rank] = (float)lane;
    }
}

extern "C" void kernel_launch(void* const* d_in, const int* in_sizes, int n_in,
                              void* d_out, int out_size, void* d_ws, size_t ws_size,
                              hipStream_t stream) {
    const float* pred_boxes = (const float*)d_in[1];
    const float* logits_b   = (const float*)d_in[2];
    const float* tgt_boxes  = (const float*)d_in[3];

    float* C    = (float*)d_out;                   // [BS,NQ,NT]
    float* rows = C + (size_t)BS * NQ * NT;        // [BS,NT]
    float* cols = rows + (size_t)BS * NT;          // [BS,NT]

    const int total = BS * NQ * NT;
    cost_kernel<<<(total + 255) / 256, 256, 0, stream>>>(pred_boxes, logits_b, tgt_boxes, C);
    lsa_kernel<<<BS, 64, 0, stream>>>(C, rows, cols);
}